// Round 2
// baseline (190.126 us; speedup 1.0000x reference)
//
#include <hip/hip_runtime.h>
#include <hip/hip_bf16.h>
#include <stdint.h>

#define DEV __device__ __forceinline__

typedef short short8 __attribute__((ext_vector_type(8)));
typedef float floatx4 __attribute__((ext_vector_type(4)));

constexpr int D = 256;
constexpr int NTOK = 8192;
constexpr int MTOT = 4 * NTOK;  // 32768 rows total

DEV void gl_lds16(const void* g, void* l) {
  __builtin_amdgcn_global_load_lds(
      (const __attribute__((address_space(1))) void*)g,
      (__attribute__((address_space(3))) void*)l, 16, 0, 0);
}

DEV float bflo(uint32_t u) { return __uint_as_float(u << 16); }
DEV float bfhi(uint32_t u) { return __uint_as_float(u & 0xffff0000u); }
DEV uint32_t packbf(float a, float b) {
  uint16_t xa = __builtin_bit_cast(uint16_t, __float2bfloat16(a));
  uint16_t xb = __builtin_bit_cast(uint16_t, __float2bfloat16(b));
  return (uint32_t)xa | ((uint32_t)xb << 16);
}

// ---------------- Kernel 0: fp32 -> bf16 conversion of phi, Wq, Wk, Wv, Wo + ns zeroing -----
constexpr int PHI_E = MTOT * D;          // 8388608
constexpr int W_E = D * D;               // 65536
__global__ __launch_bounds__(256) void convert(
    const float* __restrict__ phi, const float* __restrict__ Wq,
    const float* __restrict__ Wk, const float* __restrict__ Wv,
    const float* __restrict__ Wo,
    uint32_t* __restrict__ dst, float2* __restrict__ nszero) {
  if (blockIdx.x == 0) {
    const float2 z = {0.f, 0.f};
#pragma unroll
    for (int k = 0; k < 4; k++) nszero[k * 256 + threadIdx.x] = z;
  }
  const int idx2 = blockIdx.x * 256 + threadIdx.x;  // pair index
  const int e0 = idx2 * 2;
  float2 v;
  if (e0 < PHI_E) {
    v = ((const float2*)phi)[idx2];
  } else {
    int r = e0 - PHI_E;
    if (r < W_E) v = ((const float2*)Wq)[r >> 1];
    else if (r < 2 * W_E) v = ((const float2*)Wk)[(r - W_E) >> 1];
    else if (r < 3 * W_E) v = ((const float2*)Wv)[(r - 2 * W_E) >> 1];
    else v = ((const float2*)Wo)[(r - 3 * W_E) >> 1];
  }
  dst[idx2] = packbf(v.x, v.y);
}

// ---------------- Kernel 1: fused QKV GEMM, 128x256 tile per block --------------------------
// Q written row-major [tok][d]; K,V written TRANSPOSED [b][col][tok] (token-pair uint2).
__global__ __launch_bounds__(256, 2) void gemm_qkv(
    const __hip_bfloat16* __restrict__ phi,
    const __hip_bfloat16* __restrict__ W16,
    const float* __restrict__ bq, const float* __restrict__ bk, const float* __restrict__ bv,
    const float* __restrict__ coords, const float* __restrict__ wts,
    const float* __restrict__ lift,
    __hip_bfloat16* __restrict__ Qb, __hip_bfloat16* __restrict__ Kb,
    __hip_bfloat16* __restrict__ Vb, float* __restrict__ nsk, float* __restrict__ nsv) {
  __shared__ __align__(16) char As[8192];
  __shared__ __align__(16) char Bs[16384];
  const int t = threadIdx.x, lane = t & 63, wid = t >> 6;
  const int wm = (wid & 1) * 64, wn = (wid >> 1) * 64;
  const int l16 = lane & 15, q4 = lane >> 4;
  // XCD swizzle: mats iterate fastest within an XCD's share -> phi tile L2-reused x3
  const int bid = blockIdx.x;
  const int g = (bid & 7) * 96 + (bid >> 3);
  const int mat = g % 3;
  const int m0 = (g / 3) * 128;
  const __hip_bfloat16* W = W16 + (size_t)mat * W_E;
  const float* bias = (mat == 0) ? bq : (mat == 1) ? bk : bv;

  floatx4 acc[4][8] = {};

  const int srow = wid * 16 + (lane >> 2);
  const int skoff = (lane & 3) * 8;
  const __hip_bfloat16* gA = phi + (size_t)(m0 + srow) * D + skoff;
  const __hip_bfloat16* gB = W + (size_t)srow * D + skoff;
  char* lA = As + srow * 64 + skoff * 2;
  char* lB = Bs + srow * 64 + skoff * 2;

  for (int kt = 0; kt < 256; kt += 32) {
    gl_lds16(gA + kt, lA);
    gl_lds16(gA + kt + 64 * D, lA + 4096);
    gl_lds16(gB + kt, lB);
    gl_lds16(gB + kt + 64 * D, lB + 4096);
    gl_lds16(gB + kt + 128 * D, lB + 8192);
    gl_lds16(gB + kt + 192 * D, lB + 12288);
    __syncthreads();
    short8 af[4], bf8[8];
#pragma unroll
    for (int i = 0; i < 4; i++)
      af[i] = *(const short8*)(As + (wm + i * 16 + l16) * 64 + q4 * 16);
#pragma unroll
    for (int j = 0; j < 8; j++) {
      const int col = wn + (j & 3) * 16 + (j >> 2) * 128 + l16;
      bf8[j] = *(const short8*)(Bs + col * 64 + q4 * 16);
    }
#pragma unroll
    for (int i = 0; i < 4; i++)
#pragma unroll
      for (int j = 0; j < 8; j++)
        acc[i][j] = __builtin_amdgcn_mfma_f32_16x16x32_bf16(af[i], bf8[j], acc[i][j], 0, 0, 0);
    __syncthreads();
  }

  float bcol[8];
#pragma unroll
  for (int j = 0; j < 8; j++)
    bcol[j] = bias[wn + (j & 3) * 16 + (j >> 2) * 128 + l16];

  if (mat == 0) {
    float lx[4], ly[4], lz[4];
#pragma unroll
    for (int jj = 0; jj < 4; jj++) {
      const int c = wn + jj * 16 + l16;
      lx[jj] = lift[c * 3 + 0]; ly[jj] = lift[c * 3 + 1]; lz[jj] = lift[c * 3 + 2];
    }
#pragma unroll
    for (int i = 0; i < 4; i++) {
#pragma unroll
      for (int r = 0; r < 4; r++) {
        const int row = m0 + wm + i * 16 + q4 * 4 + r;
        const float cx = coords[row * 3 + 0];
        const float cy = coords[row * 3 + 1];
        const float cz = coords[row * 3 + 2];
#pragma unroll
        for (int jj = 0; jj < 4; jj++) {
          const int c = wn + jj * 16 + l16;
          const float p = cx * lx[jj] + cy * ly[jj] + cz * lz[jj];
          float s, cs;
          __sincosf(p, &s, &cs);
          const float f1 = acc[i][jj][r] + bcol[jj];
          const float f2 = acc[i][jj + 4][r] + bcol[jj + 4];
          Qb[(size_t)row * D + c]       = __float2bfloat16(f1 * cs - f2 * s);
          Qb[(size_t)row * D + c + 128] = __float2bfloat16(f1 * s + f2 * cs);
        }
      }
    }
  } else {
    const int b = m0 >> 13;
    const int tloc = (m0 & 8191) + wm;   // local token base of this wave
    float* ns = (mat == 1) ? nsk : nsv;
    uint32_t* T32 = (uint32_t*)((mat == 1) ? Kb : Vb);  // [b][256][4096] dwords
    float colsum[8] = {};
#pragma unroll
    for (int i = 0; i < 4; i++) {
      float w4[4];
      float psi[8][4];
#pragma unroll
      for (int r = 0; r < 4; r++) {
        const int row = m0 + wm + i * 16 + q4 * 4 + r;
        w4[r] = wts[row];
#pragma unroll
        for (int j = 0; j < 8; j++) {
          const float p = acc[i][j][r] + bcol[j];
          psi[j][r] = p;
          colsum[j] += w4[r] * p * p;
        }
      }
      const int tl = tloc + i * 16 + q4 * 4;  // multiple of 4
#pragma unroll
      for (int j = 0; j < 8; j++) {
        const int col = wn + (j & 3) * 16 + (j >> 2) * 128 + l16;
        uint2 pk;
        pk.x = packbf(psi[j][0], psi[j][1]);
        pk.y = packbf(psi[j][2], psi[j][3]);
        *(uint2*)&T32[(((size_t)b * 256 + col) << 12) + (tl >> 1)] = pk;
      }
    }
#pragma unroll
    for (int j = 0; j < 8; j++) {
      float s = colsum[j];
      s += __shfl_xor(s, 16);
      s += __shfl_xor(s, 32);
      if (q4 == 0) {
        const int col = wn + (j & 3) * 16 + (j >> 2) * 128 + l16;
        atomicAdd(&ns[b * D + col], s);
      }
    }
  }
}

// ---------------- Kernel 2: K pointwise (norm + rotary + weight), in-place on K_T -----------
// grid (128 colpairs, 4 token-chunks, 4 b); rows (c, c+128) processed together.
__global__ __launch_bounds__(256) void kpoint(
    uint32_t* __restrict__ KT32, const float* __restrict__ coords,
    const float* __restrict__ wts, const float* __restrict__ lift,
    const float* __restrict__ nsk) {
  const int c = blockIdx.x, b = blockIdx.z;
  const int tok0 = blockIdx.y * 2048;  // local token base
  const float lx = lift[c * 3 + 0], ly = lift[c * 3 + 1], lz = lift[c * 3 + 2];
  const float ik0 = rsqrtf(nsk[b * D + c] + 1e-5f);
  const float ik1 = rsqrtf(nsk[b * D + c + 128] + 1e-5f);
  const size_t rlo = ((size_t)b * 256 + c) << 12;
  const size_t rhi = rlo + ((size_t)128 << 12);
  const int t = threadIdx.x;
#pragma unroll
  for (int it = 0; it < 4; it++) {
    const int dw = (tok0 >> 1) + it * 256 + t;     // dword index within row
    const size_t gtok = (size_t)b * NTOK + dw * 2; // global even token
    const float cx0 = coords[gtok * 3 + 0], cy0 = coords[gtok * 3 + 1], cz0 = coords[gtok * 3 + 2];
    const float cx1 = coords[gtok * 3 + 3], cy1 = coords[gtok * 3 + 4], cz1 = coords[gtok * 3 + 5];
    float s0, co0, s1, co1;
    __sincosf(cx0 * lx + cy0 * ly + cz0 * lz, &s0, &co0);
    __sincosf(cx1 * lx + cy1 * ly + cz1 * lz, &s1, &co1);
    const float w0 = wts[gtok], w1 = wts[gtok + 1];
    const uint32_t lo = KT32[rlo + dw], hi = KT32[rhi + dw];
    const float f1e = bflo(lo) * ik0, f1o = bfhi(lo) * ik0;
    const float f2e = bflo(hi) * ik1, f2o = bfhi(hi) * ik1;
    KT32[rlo + dw] = packbf((f1e * co0 - f2e * s0) * w0, (f1o * co1 - f2o * s1) * w1);
    KT32[rhi + dw] = packbf((f1e * s0 + f2e * co0) * w0, (f1o * s1 + f2o * co1) * w1);
  }
}

// ---------------- Kernel 3: part[chunk][b] partial K^T V, clean gl_lds16 GEMM ---------------
// A = K_T [b][d][tok], B = V_T [b][e][tok]; K dim = 512-token chunk; out 128x128 per block.
__global__ __launch_bounds__(256, 2) void gemm_tn(
    const __hip_bfloat16* __restrict__ KT, const __hip_bfloat16* __restrict__ VT,
    __hip_bfloat16* __restrict__ part) {
  __shared__ __align__(16) char As[8192];
  __shared__ __align__(16) char Bs[8192];
  const int t = threadIdx.x, lane = t & 63, wid = t >> 6;
  const int wm = (wid & 1) * 64, wn = (wid >> 1) * 64;
  const int l16 = lane & 15, q4 = lane >> 4;
  // XCD swizzle: the 4 ed-blocks of one (chunk,b) are adjacent -> L2-share K/V tiles
  const int bid = blockIdx.x;
  const int g = (bid & 7) * 32 + (bid >> 3);
  const int ed = g & 3, chunk = (g >> 2) & 15, b = g >> 6;
  const int d0 = (ed >> 1) * 128, e0 = (ed & 1) * 128;
  const int srow = wid * 16 + (lane >> 2);
  const int skoff = (lane & 3) * 8;
  const int tokb = chunk * 512;
  const __hip_bfloat16* gA = KT + (((size_t)b * 256 + d0 + srow) << 13) + tokb + skoff;
  const __hip_bfloat16* gB = VT + (((size_t)b * 256 + e0 + srow) << 13) + tokb + skoff;
  char* lA = As + srow * 64 + skoff * 2;
  char* lB = Bs + srow * 64 + skoff * 2;
  floatx4 acc[4][4] = {};
  for (int kt = 0; kt < 512; kt += 32) {
    gl_lds16(gA + kt, lA);
    gl_lds16(gA + kt + ((size_t)64 << 13), lA + 4096);
    gl_lds16(gB + kt, lB);
    gl_lds16(gB + kt + ((size_t)64 << 13), lB + 4096);
    __syncthreads();
    short8 af[4], bf8[4];
#pragma unroll
    for (int i = 0; i < 4; i++) {
      af[i]  = *(const short8*)(As + (wm + i * 16 + l16) * 64 + q4 * 16);
      bf8[i] = *(const short8*)(Bs + (wn + i * 16 + l16) * 64 + q4 * 16);
    }
#pragma unroll
    for (int i = 0; i < 4; i++)
#pragma unroll
      for (int j = 0; j < 4; j++)
        acc[i][j] = __builtin_amdgcn_mfma_f32_16x16x32_bf16(af[i], bf8[j], acc[i][j], 0, 0, 0);
    __syncthreads();
  }
  __hip_bfloat16* pt = part + (((size_t)(chunk * 4 + b)) << 16);
#pragma unroll
  for (int j = 0; j < 4; j++) {
    const int cg = e0 + wn + j * 16 + l16;          // V column (e)
#pragma unroll
    for (int i = 0; i < 4; i++) {
      const int rg = d0 + wm + i * 16 + q4 * 4;     // K column (d)
#pragma unroll
      for (int r = 0; r < 4; r++)
        pt[(rg + r) * 256 + cg] = __float2bfloat16(acc[i][j][r]);
    }
  }
}

// ---------------- Kernel 4: Ps[b][d][e] = bf16( iv[e] * sum_chunks part[chunk][b] ) ---------
__global__ __launch_bounds__(256) void reduce_kvt(const uint32_t* __restrict__ part,
                                                  uint32_t* __restrict__ Ps,
                                                  const float* __restrict__ nsv) {
  const int flat2 = blockIdx.x * 256 + threadIdx.x;  // dword index over [4][32768]
  const int b = flat2 >> 15;
  const int off = flat2 & 32767;
  const int es = (off & 127) * 2;                    // e column pair
  float sx = 0, sy = 0;
#pragma unroll
  for (int c = 0; c < 16; c++) {
    const uint32_t u = part[(((size_t)(c * 4 + b)) << 15) + off];
    sx += bflo(u); sy += bfhi(u);
  }
  const float iv0 = rsqrtf(nsv[b * D + es] + 1e-5f);
  const float iv1 = rsqrtf(nsv[b * D + es + 1] + 1e-5f);
  Ps[flat2] = packbf(sx * iv0, sy * iv1);
}

// ---------------- Kernel 4b: MT[b][j][k] = bf16( sum_e Wo16[j,e] * Ps[b][k,e] ) -------------
__global__ __launch_bounds__(256, 2) void gemm_mt(
    const __hip_bfloat16* __restrict__ Wo16, const __hip_bfloat16* __restrict__ Ps,
    __hip_bfloat16* __restrict__ MT) {
  __shared__ __align__(16) char As[8192];
  __shared__ __align__(16) char Bs[8192];
  const int t = threadIdx.x, lane = t & 63, wid = t >> 6;
  const int wm = (wid & 1) * 64, wn = (wid >> 1) * 64;
  const int l16 = lane & 15, q4 = lane >> 4;
  const int m0 = blockIdx.x * 128, n0 = blockIdx.y * 128, b = blockIdx.z;
  const __hip_bfloat16* Bm = Ps + ((size_t)b << 16);
  floatx4 acc[4][4] = {};
  const int srow = wid * 16 + (lane >> 2);
  const int skoff = (lane & 3) * 8;
  const __hip_bfloat16* gA = Wo16 + (size_t)(m0 + srow) * D + skoff;
  const __hip_bfloat16* gB = Bm + (size_t)(n0 + srow) * D + skoff;
  char* lA = As + srow * 64 + skoff * 2;
  char* lB = Bs + srow * 64 + skoff * 2;
  for (int kt = 0; kt < 256; kt += 32) {
    gl_lds16(gA + kt, lA);
    gl_lds16(gA + kt + 64 * D, lA + 4096);
    gl_lds16(gB + kt, lB);
    gl_lds16(gB + kt + 64 * D, lB + 4096);
    __syncthreads();
    short8 af[4], bf8[4];
#pragma unroll
    for (int i = 0; i < 4; i++) {
      af[i]  = *(const short8*)(As + (wm + i * 16 + l16) * 64 + q4 * 16);
      bf8[i] = *(const short8*)(Bs + (wn + i * 16 + l16) * 64 + q4 * 16);
    }
#pragma unroll
    for (int i = 0; i < 4; i++)
#pragma unroll
      for (int j = 0; j < 4; j++)
        acc[i][j] = __builtin_amdgcn_mfma_f32_16x16x32_bf16(af[i], bf8[j], acc[i][j], 0, 0, 0);
    __syncthreads();
  }
  __hip_bfloat16* Ob = MT + ((size_t)b << 16);
#pragma unroll
  for (int j = 0; j < 4; j++) {
    const int colg = n0 + wn + j * 16 + l16;
#pragma unroll
    for (int i = 0; i < 4; i++) {
      const int rowg = m0 + wm + i * 16 + q4 * 4;
#pragma unroll
      for (int r = 0; r < 4; r++)
        Ob[(size_t)(rowg + r) * D + colg] = __float2bfloat16(acc[i][j][r]);
    }
  }
}

// ---------------- Kernel 5: out = q_rot @ MT^T + bo  (fp32 out to d_out) --------------------
__global__ __launch_bounds__(256, 2) void gemm_out(
    const __hip_bfloat16* __restrict__ A, const __hip_bfloat16* __restrict__ Pm,
    const float* __restrict__ bo, float* __restrict__ Og) {
  __shared__ __align__(16) char As[8192];
  __shared__ __align__(16) char Bs[8192];
  const int t = threadIdx.x, lane = t & 63, wid = t >> 6;
  const int wm = (wid & 1) * 64, wn = (wid >> 1) * 64;
  const int l16 = lane & 15, q4 = lane >> 4;
  const int m0 = blockIdx.x * 128, n0 = blockIdx.y * 128;
  const int b = m0 >> 13;
  const __hip_bfloat16* W = Pm + ((size_t)b << 16);
  floatx4 acc[4][4] = {};
  const int srow = wid * 16 + (lane >> 2);
  const int skoff = (lane & 3) * 8;
  const __hip_bfloat16* gA = A + (size_t)(m0 + srow) * D + skoff;
  const __hip_bfloat16* gB = W + (size_t)(n0 + srow) * D + skoff;
  char* lA = As + srow * 64 + skoff * 2;
  char* lB = Bs + srow * 64 + skoff * 2;
  for (int kt = 0; kt < 256; kt += 32) {
    gl_lds16(gA + kt, lA);
    gl_lds16(gA + kt + 64 * D, lA + 4096);
    gl_lds16(gB + kt, lB);
    gl_lds16(gB + kt + 64 * D, lB + 4096);
    __syncthreads();
    short8 af[4], bf8[4];
#pragma unroll
    for (int i = 0; i < 4; i++) {
      af[i]  = *(const short8*)(As + (wm + i * 16 + l16) * 64 + q4 * 16);
      bf8[i] = *(const short8*)(Bs + (wn + i * 16 + l16) * 64 + q4 * 16);
    }
#pragma unroll
    for (int i = 0; i < 4; i++)
#pragma unroll
      for (int j = 0; j < 4; j++)
        acc[i][j] = __builtin_amdgcn_mfma_f32_16x16x32_bf16(af[i], bf8[j], acc[i][j], 0, 0, 0);
    __syncthreads();
  }
#pragma unroll
  for (int j = 0; j < 4; j++) {
    const int colg = n0 + wn + j * 16 + l16;
    const float bb = bo[colg];
#pragma unroll
    for (int i = 0; i < 4; i++) {
      const int rowg = m0 + wm + i * 16 + q4 * 4;
#pragma unroll
      for (int r = 0; r < 4; r++)
        Og[(size_t)(rowg + r) * D + colg] = acc[i][j][r] + bb;
    }
  }
}

extern "C" void kernel_launch(void* const* d_in, const int* in_sizes, int n_in,
                              void* d_out, int out_size, void* d_ws, size_t ws_size,
                              hipStream_t stream) {
  const float* phi    = (const float*)d_in[0];
  const float* coords = (const float*)d_in[1];
  const float* wts    = (const float*)d_in[2];
  const float* bq     = (const float*)d_in[4];
  const float* bk     = (const float*)d_in[6];
  const float* bv     = (const float*)d_in[8];
  const float* Wo     = (const float*)d_in[9];
  const float* bo     = (const float*)d_in[10];
  const float* lift   = (const float*)d_in[11];

  char* ws = (char*)d_ws;
  __hip_bfloat16* phi16 = (__hip_bfloat16*)ws;                 // 16 MiB
  __hip_bfloat16* W16   = (__hip_bfloat16*)(ws + 16777216);    // 4 x 128 KiB (Wq,Wk,Wv,Wo)
  const size_t QOFF = 17301504;
  const size_t SZ = (size_t)MTOT * D * 2;  // 16 MiB per bf16 buffer
  __hip_bfloat16* Qb = (__hip_bfloat16*)(ws + QOFF);
  __hip_bfloat16* Kb = (__hip_bfloat16*)(ws + QOFF + SZ);      // transposed [b][col][tok]
  __hip_bfloat16* Vb = (__hip_bfloat16*)(ws + QOFF + 2 * SZ);  // transposed [b][col][tok]
  const size_t NOFF = QOFF + 3 * SZ;
  float* nsk = (float*)(ws + NOFF);
  float* nsv = (float*)(ws + NOFF + 4096);
  __hip_bfloat16* part = (__hip_bfloat16*)(ws + NOFF + 8192);                 // 8 MiB bf16
  __hip_bfloat16* Ps   = (__hip_bfloat16*)(ws + NOFF + 8192 + 16777216);      // 512 KiB
  __hip_bfloat16* MT   = (__hip_bfloat16*)(ws + NOFF + 8192 + 16777216 + 524288);  // 512 KiB

  convert<<<16896, 256, 0, stream>>>(phi, (const float*)d_in[3], (const float*)d_in[5],
                                     (const float*)d_in[7], Wo,
                                     (uint32_t*)ws, (float2*)(ws + NOFF));
  gemm_qkv<<<768, 256, 0, stream>>>(phi16, W16, bq, bk, bv, coords, wts, lift,
                                    Qb, Kb, Vb, nsk, nsv);
  kpoint<<<dim3(128, 4, 4), 256, 0, stream>>>((uint32_t*)Kb, coords, wts, lift, nsk);
  gemm_tn<<<256, 256, 0, stream>>>(Kb, Vb, part);
  reduce_kvt<<<512, 256, 0, stream>>>((const uint32_t*)part, (uint32_t*)Ps, nsv);
  gemm_mt<<<dim3(2, 2, 4), 256, 0, stream>>>(W16 + 3 * W_E, Ps, MT);
  gemm_out<<<dim3(256, 2), 256, 0, stream>>>(Qb, MT, bo, (float*)d_out);
}

// Round 5
// 187.762 us; speedup vs baseline: 1.0126x; 1.0126x over previous
//
#include <hip/hip_runtime.h>
#include <hip/hip_bf16.h>
#include <stdint.h>

#define DEV __device__ __forceinline__

typedef short short8 __attribute__((ext_vector_type(8)));
typedef float floatx4 __attribute__((ext_vector_type(4)));
typedef uint32_t uint32x4 __attribute__((ext_vector_type(4)));

constexpr int D = 256;
constexpr int NTOK = 8192;
constexpr int MTOT = 4 * NTOK;  // 32768 rows total

DEV void gl_lds16(const void* g, void* l) {
  __builtin_amdgcn_global_load_lds(
      (const __attribute__((address_space(1))) void*)g,
      (__attribute__((address_space(3))) void*)l, 16, 0, 0);
}

DEV float bflo(uint32_t u) { return __uint_as_float(u << 16); }
DEV float bfhi(uint32_t u) { return __uint_as_float(u & 0xffff0000u); }
DEV uint32_t packbf(float a, float b) {
  uint16_t xa = __builtin_bit_cast(uint16_t, __float2bfloat16(a));
  uint16_t xb = __builtin_bit_cast(uint16_t, __float2bfloat16(b));
  return (uint32_t)xa | ((uint32_t)xb << 16);
}

// ---------------- Kernel 0: fp32 -> bf16 conversion of phi, Wq, Wk, Wv, Wo + ns zeroing -----
constexpr int PHI_E = MTOT * D;          // 8388608
constexpr int W_E = D * D;               // 65536
__global__ __launch_bounds__(256) void convert(
    const float* __restrict__ phi, const float* __restrict__ Wq,
    const float* __restrict__ Wk, const float* __restrict__ Wv,
    const float* __restrict__ Wo,
    uint32_t* __restrict__ dst, float2* __restrict__ nszero) {
  if (blockIdx.x == 0) {
    const float2 z = {0.f, 0.f};
#pragma unroll
    for (int k = 0; k < 4; k++) nszero[k * 256 + threadIdx.x] = z;
  }
  const int idx2 = blockIdx.x * 256 + threadIdx.x;  // pair index
  const int e0 = idx2 * 2;
  float2 v;
  if (e0 < PHI_E) {
    v = ((const float2*)phi)[idx2];
  } else {
    int r = e0 - PHI_E;
    if (r < W_E) v = ((const float2*)Wq)[r >> 1];
    else if (r < 2 * W_E) v = ((const float2*)Wk)[(r - W_E) >> 1];
    else if (r < 3 * W_E) v = ((const float2*)Wv)[(r - 2 * W_E) >> 1];
    else v = ((const float2*)Wo)[(r - 3 * W_E) >> 1];
  }
  dst[idx2] = packbf(v.x, v.y);
}

// ---------------- Kernel 1: fused QKV GEMM, 128x256 tile per block --------------------------
// Q written row-major [tok][d]; K,V written TRANSPOSED [b][col][tok].
// K/V stores go through a per-wave LDS transpose so global stores are 8x128B coalesced
// segments (round-2's direct 8B/lane scatter at 16KB stride caused 40MB write amplification).
__global__ __launch_bounds__(256, 2) void gemm_qkv(
    const __hip_bfloat16* __restrict__ phi,
    const __hip_bfloat16* __restrict__ W16,
    const float* __restrict__ bq, const float* __restrict__ bk, const float* __restrict__ bv,
    const float* __restrict__ coords, const float* __restrict__ wts,
    const float* __restrict__ lift,
    __hip_bfloat16* __restrict__ Qb, __hip_bfloat16* __restrict__ Kb,
    __hip_bfloat16* __restrict__ Vb, float* __restrict__ nsk, float* __restrict__ nsv) {
  // union: [As 8192 | Bs 16384] during K-loop; 4 x 9216B per-wave transpose buf in epilogue
  __shared__ __align__(16) char Smem[36864];
  char* As = Smem;
  char* Bs = Smem + 8192;
  const int t = threadIdx.x, lane = t & 63, wid = t >> 6;
  const int wm = (wid & 1) * 64, wn = (wid >> 1) * 64;
  const int l16 = lane & 15, q4 = lane >> 4;
  // XCD swizzle: mats iterate fastest within an XCD's share -> phi tile L2-reused x3
  const int bid = blockIdx.x;
  const int g = (bid & 7) * 96 + (bid >> 3);
  const int mat = g % 3;
  const int m0 = (g / 3) * 128;
  const __hip_bfloat16* W = W16 + (size_t)mat * W_E;
  const float* bias = (mat == 0) ? bq : (mat == 1) ? bk : bv;

  floatx4 acc[4][8] = {};

  const int srow = wid * 16 + (lane >> 2);
  const int skoff = (lane & 3) * 8;
  const __hip_bfloat16* gA = phi + (size_t)(m0 + srow) * D + skoff;
  const __hip_bfloat16* gB = W + (size_t)srow * D + skoff;
  char* lA = As + srow * 64 + skoff * 2;
  char* lB = Bs + srow * 64 + skoff * 2;

  for (int kt = 0; kt < 256; kt += 32) {
    gl_lds16(gA + kt, lA);
    gl_lds16(gA + kt + 64 * D, lA + 4096);
    gl_lds16(gB + kt, lB);
    gl_lds16(gB + kt + 64 * D, lB + 4096);
    gl_lds16(gB + kt + 128 * D, lB + 8192);
    gl_lds16(gB + kt + 192 * D, lB + 12288);
    __syncthreads();
    short8 af[4], bf8[8];
#pragma unroll
    for (int i = 0; i < 4; i++)
      af[i] = *(const short8*)(As + (wm + i * 16 + l16) * 64 + q4 * 16);
#pragma unroll
    for (int j = 0; j < 8; j++) {
      const int col = wn + (j & 3) * 16 + (j >> 2) * 128 + l16;
      bf8[j] = *(const short8*)(Bs + col * 64 + q4 * 16);
    }
#pragma unroll
    for (int i = 0; i < 4; i++)
#pragma unroll
      for (int j = 0; j < 8; j++)
        acc[i][j] = __builtin_amdgcn_mfma_f32_16x16x32_bf16(af[i], bf8[j], acc[i][j], 0, 0, 0);
    __syncthreads();
  }

  float bcol[8];
#pragma unroll
  for (int j = 0; j < 8; j++)
    bcol[j] = bias[wn + (j & 3) * 16 + (j >> 2) * 128 + l16];

  if (mat == 0) {
    float lx[4], ly[4], lz[4];
#pragma unroll
    for (int jj = 0; jj < 4; jj++) {
      const int c = wn + jj * 16 + l16;
      lx[jj] = lift[c * 3 + 0]; ly[jj] = lift[c * 3 + 1]; lz[jj] = lift[c * 3 + 2];
    }
#pragma unroll
    for (int i = 0; i < 4; i++) {
#pragma unroll
      for (int r = 0; r < 4; r++) {
        const int row = m0 + wm + i * 16 + q4 * 4 + r;
        const float cx = coords[row * 3 + 0];
        const float cy = coords[row * 3 + 1];
        const float cz = coords[row * 3 + 2];
#pragma unroll
        for (int jj = 0; jj < 4; jj++) {
          const int c = wn + jj * 16 + l16;
          const float p = cx * lx[jj] + cy * ly[jj] + cz * lz[jj];
          float s, cs;
          __sincosf(p, &s, &cs);
          const float f1 = acc[i][jj][r] + bcol[jj];
          const float f2 = acc[i][jj + 4][r] + bcol[jj + 4];
          Qb[(size_t)row * D + c]       = __float2bfloat16(f1 * cs - f2 * s);
          Qb[(size_t)row * D + c + 128] = __float2bfloat16(f1 * s + f2 * cs);
        }
      }
    }
  } else {
    const int b = m0 >> 13;
    const int tl0 = (m0 & 8191) + wm;   // wave's local token base (multiple of 64)
    float* ns = (mat == 1) ? nsk : nsv;
    __hip_bfloat16* Tb = (mat == 1) ? Kb : Vb;   // [b][256][8192]
    char* myT = Smem + wid * 9216;               // 64 rows x 144B (128B data + 16B pad)
    const int tc = lane & 7;                     // 16B token-chunk within 128B row
    const int clb = lane >> 3;                   // 0..7
    float colsum[8] = {};
#pragma unroll
    for (int h = 0; h < 2; h++) {                // column halves: cols wn+cl+h*128
#pragma unroll
      for (int i = 0; i < 4; i++) {
        float w4[4];
#pragma unroll
        for (int r = 0; r < 4; r++) w4[r] = wts[m0 + wm + i * 16 + q4 * 4 + r];
#pragma unroll
        for (int jj = 0; jj < 4; jj++) {
          const int j = h * 4 + jj;
          const float p0 = acc[i][j][0] + bcol[j];
          const float p1 = acc[i][j][1] + bcol[j];
          const float p2 = acc[i][j][2] + bcol[j];
          const float p3 = acc[i][j][3] + bcol[j];
          colsum[j] += w4[0] * p0 * p0 + w4[1] * p1 * p1 + w4[2] * p2 * p2 + w4[3] * p3 * p3;
          const int cl = jj * 16 + l16;          // 0..63 local col
          uint2 pk;
          pk.x = packbf(p0, p1);
          pk.y = packbf(p2, p3);
          *(uint2*)(myT + cl * 144 + i * 32 + q4 * 8) = pk;
        }
      }
      __syncthreads();                           // drain LDS writes before cross-lane reads
#pragma unroll
      for (int s = 0; s < 8; s++) {
        const int cl = s * 8 + clb;
        const int col = wn + cl + h * 128;
        const uint32x4 vv = *(const uint32x4*)(myT + cl * 144 + tc * 16);
        *(uint32x4*)((char*)Tb + ((((size_t)b * 256 + col) << 13) + tl0 + tc * 8) * 2) = vv;
      }
      if (h == 0) __syncthreads();               // protect per-wave buf reuse ordering
    }
#pragma unroll
    for (int j = 0; j < 8; j++) {
      float s = colsum[j];
      s += __shfl_xor(s, 16);
      s += __shfl_xor(s, 32);
      if (q4 == 0) {
        const int col = wn + (j & 3) * 16 + (j >> 2) * 128 + l16;
        atomicAdd(&ns[b * D + col], s);
      }
    }
  }
}

// ---------------- Kernel 2: K pointwise (norm + rotary + weight), in-place on K_T -----------
// grid (128 colpairs, 4 token-chunks, 4 b); rows (c, c+128) processed together.
__global__ __launch_bounds__(256) void kpoint(
    uint32_t* __restrict__ KT32, const float* __restrict__ coords,
    const float* __restrict__ wts, const float* __restrict__ lift,
    const float* __restrict__ nsk) {
  const int c = blockIdx.x, b = blockIdx.z;
  const int tok0 = blockIdx.y * 2048;  // local token base
  const float lx = lift[c * 3 + 0], ly = lift[c * 3 + 1], lz = lift[c * 3 + 2];
  const float ik0 = rsqrtf(nsk[b * D + c] + 1e-5f);
  const float ik1 = rsqrtf(nsk[b * D + c + 128] + 1e-5f);
  const size_t rlo = ((size_t)b * 256 + c) << 12;
  const size_t rhi = rlo + ((size_t)128 << 12);
  const int t = threadIdx.x;
#pragma unroll
  for (int it = 0; it < 4; it++) {
    const int dw = (tok0 >> 1) + it * 256 + t;     // dword index within row
    const size_t gtok = (size_t)b * NTOK + dw * 2; // global even token
    const float cx0 = coords[gtok * 3 + 0], cy0 = coords[gtok * 3 + 1], cz0 = coords[gtok * 3 + 2];
    const float cx1 = coords[gtok * 3 + 3], cy1 = coords[gtok * 3 + 4], cz1 = coords[gtok * 3 + 5];
    float s0, co0, s1, co1;
    __sincosf(cx0 * lx + cy0 * ly + cz0 * lz, &s0, &co0);
    __sincosf(cx1 * lx + cy1 * ly + cz1 * lz, &s1, &co1);
    const float w0 = wts[gtok], w1 = wts[gtok + 1];
    const uint32_t lo = KT32[rlo + dw], hi = KT32[rhi + dw];
    const float f1e = bflo(lo) * ik0, f1o = bfhi(lo) * ik0;
    const float f2e = bflo(hi) * ik1, f2o = bfhi(hi) * ik1;
    KT32[rlo + dw] = packbf((f1e * co0 - f2e * s0) * w0, (f1o * co1 - f2o * s1) * w1);
    KT32[rhi + dw] = packbf((f1e * s0 + f2e * co0) * w0, (f1o * s1 + f2o * co1) * w1);
  }
}

// ---------------- Kernel 3: part[chunk][b] partial K^T V, clean gl_lds16 GEMM ---------------
// A = K_T [b][d][tok], B = V_T [b][e][tok]; K dim = 512-token chunk; out 128x128 per block.
__global__ __launch_bounds__(256, 2) void gemm_tn(
    const __hip_bfloat16* __restrict__ KT, const __hip_bfloat16* __restrict__ VT,
    __hip_bfloat16* __restrict__ part) {
  __shared__ __align__(16) char As[8192];
  __shared__ __align__(16) char Bs[8192];
  const int t = threadIdx.x, lane = t & 63, wid = t >> 6;
  const int wm = (wid & 1) * 64, wn = (wid >> 1) * 64;
  const int l16 = lane & 15, q4 = lane >> 4;
  // XCD swizzle: the 4 ed-blocks of one (chunk,b) are adjacent -> L2-share K/V tiles
  const int bid = blockIdx.x;
  const int g = (bid & 7) * 32 + (bid >> 3);
  const int ed = g & 3, chunk = (g >> 2) & 15, b = g >> 6;
  const int d0 = (ed >> 1) * 128, e0 = (ed & 1) * 128;
  const int srow = wid * 16 + (lane >> 2);
  const int skoff = (lane & 3) * 8;
  const int tokb = chunk * 512;
  const __hip_bfloat16* gA = KT + (((size_t)b * 256 + d0 + srow) << 13) + tokb + skoff;
  const __hip_bfloat16* gB = VT + (((size_t)b * 256 + e0 + srow) << 13) + tokb + skoff;
  char* lA = As + srow * 64 + skoff * 2;
  char* lB = Bs + srow * 64 + skoff * 2;
  floatx4 acc[4][4] = {};
  for (int kt = 0; kt < 512; kt += 32) {
    gl_lds16(gA + kt, lA);
    gl_lds16(gA + kt + ((size_t)64 << 13), lA + 4096);
    gl_lds16(gB + kt, lB);
    gl_lds16(gB + kt + ((size_t)64 << 13), lB + 4096);
    __syncthreads();
    short8 af[4], bf8[4];
#pragma unroll
    for (int i = 0; i < 4; i++) {
      af[i]  = *(const short8*)(As + (wm + i * 16 + l16) * 64 + q4 * 16);
      bf8[i] = *(const short8*)(Bs + (wn + i * 16 + l16) * 64 + q4 * 16);
    }
#pragma unroll
    for (int i = 0; i < 4; i++)
#pragma unroll
      for (int j = 0; j < 4; j++)
        acc[i][j] = __builtin_amdgcn_mfma_f32_16x16x32_bf16(af[i], bf8[j], acc[i][j], 0, 0, 0);
    __syncthreads();
  }
  __hip_bfloat16* pt = part + (((size_t)(chunk * 4 + b)) << 16);
#pragma unroll
  for (int j = 0; j < 4; j++) {
    const int cg = e0 + wn + j * 16 + l16;          // V column (e)
#pragma unroll
    for (int i = 0; i < 4; i++) {
      const int rg = d0 + wm + i * 16 + q4 * 4;     // K column (d)
#pragma unroll
      for (int r = 0; r < 4; r++)
        pt[(rg + r) * 256 + cg] = __float2bfloat16(acc[i][j][r]);
    }
  }
}

// ---------------- Kernel 4: Ps[b][d][e] = bf16( iv[e] * sum_chunks part[chunk][b] ) ---------
__global__ __launch_bounds__(256) void reduce_kvt(const uint32_t* __restrict__ part,
                                                  uint32_t* __restrict__ Ps,
                                                  const float* __restrict__ nsv) {
  const int flat2 = blockIdx.x * 256 + threadIdx.x;  // dword index over [4][32768]
  const int b = flat2 >> 15;
  const int off = flat2 & 32767;
  const int es = (off & 127) * 2;                    // e column pair
  float sx = 0, sy = 0;
#pragma unroll
  for (int c = 0; c < 16; c++) {
    const uint32_t u = part[(((size_t)(c * 4 + b)) << 15) + off];
    sx += bflo(u); sy += bfhi(u);
  }
  const float iv0 = rsqrtf(nsv[b * D + es] + 1e-5f);
  const float iv1 = rsqrtf(nsv[b * D + es + 1] + 1e-5f);
  Ps[flat2] = packbf(sx * iv0, sy * iv1);
}

// ---------------- Kernel 4b: MT[b][j][k] = bf16( sum_e Wo16[j,e] * Ps[b][k,e] ) -------------
__global__ __launch_bounds__(256, 2) void gemm_mt(
    const __hip_bfloat16* __restrict__ Wo16, const __hip_bfloat16* __restrict__ Ps,
    __hip_bfloat16* __restrict__ MT) {
  __shared__ __align__(16) char As[8192];
  __shared__ __align__(16) char Bs[8192];
  const int t = threadIdx.x, lane = t & 63, wid = t >> 6;
  const int wm = (wid & 1) * 64, wn = (wid >> 1) * 64;
  const int l16 = lane & 15, q4 = lane >> 4;
  const int m0 = blockIdx.x * 128, n0 = blockIdx.y * 128, b = blockIdx.z;
  const __hip_bfloat16* Bm = Ps + ((size_t)b << 16);
  floatx4 acc[4][4] = {};
  const int srow = wid * 16 + (lane >> 2);
  const int skoff = (lane & 3) * 8;
  const __hip_bfloat16* gA = Wo16 + (size_t)(m0 + srow) * D + skoff;
  const __hip_bfloat16* gB = Bm + (size_t)(n0 + srow) * D + skoff;
  char* lA = As + srow * 64 + skoff * 2;
  char* lB = Bs + srow * 64 + skoff * 2;
  for (int kt = 0; kt < 256; kt += 32) {
    gl_lds16(gA + kt, lA);
    gl_lds16(gA + kt + 64 * D, lA + 4096);
    gl_lds16(gB + kt, lB);
    gl_lds16(gB + kt + 64 * D, lB + 4096);
    __syncthreads();
    short8 af[4], bf8[4];
#pragma unroll
    for (int i = 0; i < 4; i++) {
      af[i]  = *(const short8*)(As + (wm + i * 16 + l16) * 64 + q4 * 16);
      bf8[i] = *(const short8*)(Bs + (wn + i * 16 + l16) * 64 + q4 * 16);
    }
#pragma unroll
    for (int i = 0; i < 4; i++)
#pragma unroll
      for (int j = 0; j < 4; j++)
        acc[i][j] = __builtin_amdgcn_mfma_f32_16x16x32_bf16(af[i], bf8[j], acc[i][j], 0, 0, 0);
    __syncthreads();
  }
  __hip_bfloat16* Ob = MT + ((size_t)b << 16);
#pragma unroll
  for (int j = 0; j < 4; j++) {
    const int colg = n0 + wn + j * 16 + l16;
#pragma unroll
    for (int i = 0; i < 4; i++) {
      const int rowg = m0 + wm + i * 16 + q4 * 4;
#pragma unroll
      for (int r = 0; r < 4; r++)
        Ob[(size_t)(rowg + r) * D + colg] = __float2bfloat16(acc[i][j][r]);
    }
  }
}

// ---------------- Kernel 5: out = q_rot @ MT^T + bo  (fp32 out to d_out) --------------------
__global__ __launch_bounds__(256, 2) void gemm_out(
    const __hip_bfloat16* __restrict__ A, const __hip_bfloat16* __restrict__ Pm,
    const float* __restrict__ bo, float* __restrict__ Og) {
  __shared__ __align__(16) char As[8192];
  __shared__ __align__(16) char Bs[8192];
  const int t = threadIdx.x, lane = t & 63, wid = t >> 6;
  const int wm = (wid & 1) * 64, wn = (wid >> 1) * 64;
  const int l16 = lane & 15, q4 = lane >> 4;
  const int m0 = blockIdx.x * 128, n0 = blockIdx.y * 128;
  const int b = m0 >> 13;
  const __hip_bfloat16* W = Pm + ((size_t)b << 16);
  floatx4 acc[4][4] = {};
  const int srow = wid * 16 + (lane >> 2);
  const int skoff = (lane & 3) * 8;
  const __hip_bfloat16* gA = A + (size_t)(m0 + srow) * D + skoff;
  const __hip_bfloat16* gB = W + (size_t)(n0 + srow) * D + skoff;
  char* lA = As + srow * 64 + skoff * 2;
  char* lB = Bs + srow * 64 + skoff * 2;
  for (int kt = 0; kt < 256; kt += 32) {
    gl_lds16(gA + kt, lA);
    gl_lds16(gA + kt + 64 * D, lA + 4096);
    gl_lds16(gB + kt, lB);
    gl_lds16(gB + kt + 64 * D, lB + 4096);
    __syncthreads();
    short8 af[4], bf8[4];
#pragma unroll
    for (int i = 0; i < 4; i++) {
      af[i]  = *(const short8*)(As + (wm + i * 16 + l16) * 64 + q4 * 16);
      bf8[i] = *(const short8*)(Bs + (wn + i * 16 + l16) * 64 + q4 * 16);
    }
#pragma unroll
    for (int i = 0; i < 4; i++)
#pragma unroll
      for (int j = 0; j < 4; j++)
        acc[i][j] = __builtin_amdgcn_mfma_f32_16x16x32_bf16(af[i], bf8[j], acc[i][j], 0, 0, 0);
    __syncthreads();
  }
#pragma unroll
  for (int j = 0; j < 4; j++) {
    const int colg = n0 + wn + j * 16 + l16;
    const float bb = bo[colg];
#pragma unroll
    for (int i = 0; i < 4; i++) {
      const int rowg = m0 + wm + i * 16 + q4 * 4;
#pragma unroll
      for (int r = 0; r < 4; r++)
        Og[(size_t)(rowg + r) * D + colg] = acc[i][j][r] + bb;
    }
  }
}

extern "C" void kernel_launch(void* const* d_in, const int* in_sizes, int n_in,
                              void* d_out, int out_size, void* d_ws, size_t ws_size,
                              hipStream_t stream) {
  const float* phi    = (const float*)d_in[0];
  const float* coords = (const float*)d_in[1];
  const float* wts    = (const float*)d_in[2];
  const float* bq     = (const float*)d_in[4];
  const float* bk     = (const float*)d_in[6];
  const float* bv     = (const float*)d_in[8];
  const float* Wo     = (const float*)d_in[9];
  const float* bo     = (const float*)d_in[10];
  const float* lift   = (const float*)d_in[11];

  char* ws = (char*)d_ws;
  __hip_bfloat16* phi16 = (__hip_bfloat16*)ws;                 // 16 MiB
  __hip_bfloat16* W16   = (__hip_bfloat16*)(ws + 16777216);    // 4 x 128 KiB (Wq,Wk,Wv,Wo)
  const size_t QOFF = 17301504;
  const size_t SZ = (size_t)MTOT * D * 2;  // 16 MiB per bf16 buffer
  __hip_bfloat16* Qb = (__hip_bfloat16*)(ws + QOFF);
  __hip_bfloat16* Kb = (__hip_bfloat16*)(ws + QOFF + SZ);      // transposed [b][col][tok]
  __hip_bfloat16* Vb = (__hip_bfloat16*)(ws + QOFF + 2 * SZ);  // transposed [b][col][tok]
  const size_t NOFF = QOFF + 3 * SZ;
  float* nsk = (float*)(ws + NOFF);
  float* nsv = (float*)(ws + NOFF + 4096);
  __hip_bfloat16* part = (__hip_bfloat16*)(ws + NOFF + 8192);                 // 8 MiB bf16
  __hip_bfloat16* Ps   = (__hip_bfloat16*)(ws + NOFF + 8192 + 16777216);      // 512 KiB
  __hip_bfloat16* MT   = (__hip_bfloat16*)(ws + NOFF + 8192 + 16777216 + 524288);  // 512 KiB

  convert<<<16896, 256, 0, stream>>>(phi, (const float*)d_in[3], (const float*)d_in[5],
                                     (const float*)d_in[7], Wo,
                                     (uint32_t*)ws, (float2*)(ws + NOFF));
  gemm_qkv<<<768, 256, 0, stream>>>(phi16, W16, bq, bk, bv, coords, wts, lift,
                                    Qb, Kb, Vb, nsk, nsv);
  kpoint<<<dim3(128, 4, 4), 256, 0, stream>>>((uint32_t*)Kb, coords, wts, lift, nsk);
  gemm_tn<<<256, 256, 0, stream>>>(Kb, Vb, part);
  reduce_kvt<<<512, 256, 0, stream>>>((const uint32_t*)part, (uint32_t*)Ps, nsv);
  gemm_mt<<<dim3(2, 2, 4), 256, 0, stream>>>(W16 + 3 * W_E, Ps, MT);
  gemm_out<<<dim3(256, 2), 256, 0, stream>>>(Qb, MT, bo, (float*)d_out);
}